// Round 9
// baseline (521.489 us; speedup 1.0000x reference)
//
#include <hip/hip_runtime.h>
#include <stdint.h>
#include <stddef.h>

#define M_TOK 8192
#define N_OUT 4096
#define K_IN  4096
#define R_LORA 16

// ---- 256x256 4-phase/tile GEMM geometry ----
#define BM 256
#define BN 256
#define BK 64
#define NT (K_IN / BK)          // 64 K-tiles

// fused prologue grid split (r4-verified)
#define WEFF_BLOCKS ((K_IN / 1024) * (N_OUT / 16))      // 4 * 256 = 1024
#define CAST_BLOCKS ((M_TOK * K_IN) / (8 * 256))        // 8 floats/thread -> 16384

typedef __bf16 bf16_t;
typedef __bf16 bf16x4 __attribute__((ext_vector_type(4)));
typedef __bf16 bf16x8 __attribute__((ext_vector_type(8)));
typedef float floatx4 __attribute__((ext_vector_type(4)));
typedef float floatx16 __attribute__((ext_vector_type(16)));

// async global->LDS, 16B per lane. LDS dest must be wave-uniform base; HW adds lane*16.
__device__ inline void async_copy16(const bf16_t* g, bf16_t* l) {
  __builtin_amdgcn_global_load_lds(
      (__attribute__((address_space(1))) void*)(uintptr_t)(const void*)g,
      (__attribute__((address_space(3))) void*)l,
      16, 0, 0);
}

#define BAR()   __builtin_amdgcn_s_barrier()
#define VMCNT8  asm volatile("s_waitcnt vmcnt(8)" ::: "memory")
#define VMCNT4  asm volatile("s_waitcnt vmcnt(4)" ::: "memory")
#define VMCNT2  asm volatile("s_waitcnt vmcnt(2)" ::: "memory")
#define VMCNT0  asm volatile("s_waitcnt vmcnt(0)" ::: "memory")

// ---------------- fused prologue (r4/r8 verbatim: cast x + Weff=W+scale*B@A) ----------------
__global__ __launch_bounds__(256) void prep_fused(
    const float* __restrict__ x, bf16_t* __restrict__ xb,
    const float* __restrict__ W, const float* __restrict__ lB,
    const float* __restrict__ lA, const float* __restrict__ scale_p,
    bf16_t* __restrict__ wb) {
  const int b = blockIdx.x;
  if (b < WEFF_BLOCKS) {
    const int kbase = (b & 3) * 1024 + threadIdx.x * 4;  // K_IN/1024 == 4
    const int o0    = (b >> 2) * 16;
    const float scale = *scale_p;

    float4 areg[R_LORA];
#pragma unroll
    for (int r = 0; r < R_LORA; ++r)
      areg[r] = *(const float4*)(lA + (size_t)r * K_IN + kbase);

    for (int oo = 0; oo < 16; ++oo) {
      const int o = o0 + oo;
      float4 w = *(const float4*)(W + (size_t)o * K_IN + kbase);
      float a0 = w.x, a1 = w.y, a2 = w.z, a3 = w.w;
#pragma unroll
      for (int r = 0; r < R_LORA; ++r) {
        float bb = lB[(size_t)o * R_LORA + r] * scale;  // block-uniform -> s_load
        a0 += bb * areg[r].x; a1 += bb * areg[r].y;
        a2 += bb * areg[r].z; a3 += bb * areg[r].w;
      }
      bf16x4 v;
      v[0] = (bf16_t)a0; v[1] = (bf16_t)a1; v[2] = (bf16_t)a2; v[3] = (bf16_t)a3;
      *(bf16x4*)(wb + (size_t)o * K_IN + kbase) = v;
    }
  } else {
    const size_t t = (size_t)(b - WEFF_BLOCKS) * 256 + threadIdx.x;
    const float4* xp = (const float4*)x + t * 2;
    float4 a0 = xp[0];
    float4 a1 = xp[1];
    bf16x8 v;
    v[0] = (bf16_t)a0.x; v[1] = (bf16_t)a0.y; v[2] = (bf16_t)a0.z; v[3] = (bf16_t)a0.w;
    v[4] = (bf16_t)a1.x; v[5] = (bf16_t)a1.y; v[6] = (bf16_t)a1.z; v[7] = (bf16_t)a1.w;
    *(bf16x8*)(xb + t * 8) = v;
  }
}

// ---------------- pass 2: C = A @ Bw^T + bias — deep-pipelined, 32x32x16 MFMA ----------------
// ROUND-9 CHANGE: 16x16x32 -> 32x32x16 MFMA. The r8 schedule (phases, read counts
// 12/4/8/0, staging units, deep vmcnt(8) ledger, swizzle, barriers) carries over
// VERBATIM — quadrant (mh,nh) consumption keeps the identical region order, so the
// race-screened sync structure is untouched. Per tile per wave: 32 MFMA (was 64),
// same 24x ds_read_b128, same register footprint (acc 8x f32x16 = 128; frags 96).
// Operand mapping (derived from our verified 16x16x32 pattern, 2xK family):
//   A: row = lane&31, k = (lane>>5)*8 + j   (B analogous, col = lane&31)
//   C/D: col = lane&31, row = (reg&3) + 8*(reg>>2) + 4*(lane>>5)   [m74/m101]
// LDS fragment read: byte = rowLDS*128 + ((ks*2 + (lane>>5)) ^ (rowLDS&7))*16.
// Per 16-lane HW group: 16 consecutive rows, one logical slot -> XOR spreads to
// 2 lanes/slot = conflict-free (m136), same as r8.
// vmcnt rotation (r8 verbatim):
//   P0: stage B1(t+1)->nxt; vmcnt(8) drains B1(t)      [read @P1]
//   P1: stage A1(t+1)->nxt; vmcnt(8) drains A1(t)      [read @P2]
//   P2: stage A0(t+2)->cur; no wait
//   P3: stage B0(t+2)->cur; vmcnt(8) drains A0,B0(t+1) [read @next P0]
__global__ __launch_bounds__(512, 2) void gemm_bt256(const bf16_t* __restrict__ A,
                                                     const bf16_t* __restrict__ Bw,
                                                     const float* __restrict__ bias,
                                                     float* __restrict__ C) {
  __shared__ bf16_t sA[2 * 2 * 128 * 64];  // 64 KB
  __shared__ bf16_t sB[2 * 2 * 128 * 64];  // 64 KB

  const int tid  = threadIdx.x;
  const int wave = tid >> 6;
  const int lane = tid & 63;
  const int lrow = lane & 31;
  const int l5   = lane >> 5;
  const int wr   = wave >> 2;   // 0..1 (M)
  const int wc   = wave & 3;    // 0..3 (N)

  // bijective XCD swizzle (512 blocks, 512 % 8 == 0)
  const int bid = blockIdx.x;
  const int swz = (bid & 7) * 64 + (bid >> 3);
  const int bn  = (swz & 15) * BN;   // N index [0,16)
  const int bm  = (swz >> 4) * BM;   // M index [0,32)

  // ---- staging source pointers (per-thread, inverse-swizzled column; r8 verbatim) ----
  const int t8  = tid >> 3;                         // 0..63
  const int col = ((tid & 7) ^ (t8 & 7)) * 8;       // inverse swizzle on source
  const bf16_t* pA00 = A + (size_t)(bm +   0 + t8) * K_IN + col;  // region0, L0
  const bf16_t* pA01 = A + (size_t)(bm + 128 + t8) * K_IN + col;  // region0, L1
  const bf16_t* pA10 = A + (size_t)(bm +  64 + t8) * K_IN + col;  // region1, L0
  const bf16_t* pA11 = A + (size_t)(bm + 192 + t8) * K_IN + col;  // region1, L1
  const int brl = (t8 >> 5) * 64 + (t8 & 31);
  const bf16_t* pB00 = Bw + (size_t)(bn +   0 + brl +  0) * K_IN + col;  // nh0, L0
  const bf16_t* pB01 = Bw + (size_t)(bn + 128 + brl +  0) * K_IN + col;  // nh0, L1
  const bf16_t* pB10 = Bw + (size_t)(bn +   0 + brl + 32) * K_IN + col;  // nh1, L0
  const bf16_t* pB11 = Bw + (size_t)(bn + 128 + brl + 32) * K_IN + col;  // nh1, L1

  // ---- fragment read base pointers (32-row blocks) ----
  // A: LDS row = wr*64 + mb*32 + lrow within region mh (region = 16384 B).
  // B: LDS row = wc*32 + lrow within region nh.
  const char* aP = (const char*)sA + (size_t)(wr * 64 + lrow) * 128;
  const char* bP = (const char*)sB + (size_t)(wc * 32 + lrow) * 128;
  const int sw7 = lrow & 7;

  floatx16 acc[4][2];
#pragma unroll
  for (int m = 0; m < 4; ++m)
#pragma unroll
    for (int n = 0; n < 2; ++n)
#pragma unroll
      for (int e = 0; e < 16; ++e) acc[m][n][e] = 0.f;

  // fragment register sets (statically indexed everywhere; footprint == r8)
  bf16x8 a0[2][4], a1[2][4], bA[4], bB[4];

#define STAGE_A0(nb) do { \
    async_copy16(pA00, sA + (nb)         + wave * 512); \
    async_copy16(pA01, sA + (nb) + 4096  + wave * 512); \
    pA00 += BK; pA01 += BK; } while (0)
#define STAGE_A1(nb) do { \
    async_copy16(pA10, sA + (nb) + 8192  + wave * 512); \
    async_copy16(pA11, sA + (nb) + 12288 + wave * 512); \
    pA10 += BK; pA11 += BK; } while (0)
#define STAGE_B0(nb) do { \
    async_copy16(pB00, sB + (nb)         + wave * 512); \
    async_copy16(pB01, sB + (nb) + 4096  + wave * 512); \
    pB00 += BK; pB01 += BK; } while (0)
#define STAGE_B1(nb) do { \
    async_copy16(pB10, sB + (nb) + 8192  + wave * 512); \
    async_copy16(pB11, sB + (nb) + 12288 + wave * 512); \
    pB10 += BK; pB11 += BK; } while (0)

// Quadrant reads: A (2 m-blocks x 4 k-steps = 8x b128), B (4 k-steps = 4x b128).
#define RD_A32(dst, mh, bofs) do { _Pragma("unroll") for (int mb = 0; mb < 2; ++mb) \
    _Pragma("unroll") for (int ks = 0; ks < 4; ++ks) \
      dst[mb][ks] = *(const bf16x8*)(aP + (bofs) + (mh) * 16384 + mb * 4096 + \
                                     (size_t)(((ks * 2 + l5) ^ sw7) * 16)); } while (0)
#define RD_B32(dst, nh, bofs) do { _Pragma("unroll") for (int ks = 0; ks < 4; ++ks) \
      dst[ks] = *(const bf16x8*)(bP + (bofs) + (nh) * 16384 + \
                                 (size_t)(((ks * 2 + l5) ^ sw7) * 16)); } while (0)

#define MM32(aset, bset, mh, nh) do { \
    __builtin_amdgcn_s_setprio(1); \
    _Pragma("unroll") for (int mb = 0; mb < 2; ++mb) \
    _Pragma("unroll") for (int ks = 0; ks < 4; ++ks) \
      acc[(mh) * 2 + mb][nh] = __builtin_amdgcn_mfma_f32_32x32x16_bf16( \
          aset[mb][ks], bset[ks], acc[(mh) * 2 + mb][nh], 0, 0, 0); \
    __builtin_amdgcn_s_setprio(0); } while (0)

// Steady tile: bo = cur-buffer byte offset, eCur/eNxt = cur/next buffer elem offsets.
#define TILE(bo, eCur, eNxt) do { \
    /* P0 */ \
    RD_A32(a0, 0, bo); RD_B32(bA, 0, bo); \
    STAGE_B1(eNxt); VMCNT8; \
    MM32(a0, bA, 0, 0); \
    BAR(); \
    /* P1 */ \
    RD_B32(bB, 1, bo); \
    STAGE_A1(eNxt); VMCNT8; \
    MM32(a0, bB, 0, 1); \
    BAR(); \
    /* P2 */ \
    RD_A32(a1, 1, bo); \
    STAGE_A0(eCur); \
    MM32(a1, bB, 1, 1); \
    BAR(); \
    /* P3 */ \
    STAGE_B0(eCur); VMCNT8; \
    MM32(a1, bA, 1, 0); \
    BAR(); \
  } while (0)

  // ---- prologue: 6 units (12 loads) in steady-state issue order ----
  STAGE_A0(0); STAGE_B0(0);            // tile0 A0,B0  (oldest)
  STAGE_B1(0); STAGE_A1(0);            // tile0 B1,A1
  STAGE_A0(16384); STAGE_B0(16384);    // tile1 A0,B0
  VMCNT8;                              // drains A0,B0(t0)
  BAR();

  for (int t = 0; t < NT - 2; t += 2) {
    TILE(0, 0, 16384);        // even tile: read buf0
    TILE(32768, 16384, 0);    // odd tile: read buf1
  }

  // ---- tile 62 (even): no t+2 stages ----
  RD_A32(a0, 0, 0); RD_B32(bA, 0, 0);
  STAGE_B1(16384); VMCNT8;             // drains B1(62)
  MM32(a0, bA, 0, 0); BAR();
  RD_B32(bB, 1, 0);
  STAGE_A1(16384); VMCNT8;             // drains A1(62)
  MM32(a0, bB, 0, 1); BAR();
  RD_A32(a1, 1, 0);
  MM32(a1, bB, 1, 1); BAR();
  VMCNT4;                              // drains A0,B0(63); leaves B1,A1(63)
  MM32(a1, bA, 1, 0); BAR();

  // ---- tile 63 (odd): no stages; drain 2 -> 0 ----
  RD_A32(a0, 0, 32768); RD_B32(bA, 0, 32768);
  VMCNT2;                              // drains B1(63)
  MM32(a0, bA, 0, 0); BAR();
  RD_B32(bB, 1, 32768);
  VMCNT0;                              // drains A1(63)
  MM32(a0, bB, 0, 1); BAR();
  RD_A32(a1, 1, 32768);
  MM32(a1, bB, 1, 1); BAR();
  MM32(a1, bA, 1, 0); BAR();
#undef TILE
#undef STAGE_A0
#undef STAGE_A1
#undef STAGE_B0
#undef STAGE_B1
#undef RD_A32
#undef RD_B32
#undef MM32

  // ---- epilogue: C col = bn + wc*64 + nb*32 + lrow;
  //                row = bm + wr*128 + mbG*32 + (reg&3) + 8*(reg>>2) + 4*l5 ----
#pragma unroll
  for (int nb = 0; nb < 2; ++nb) {
    const int colc = bn + wc * 64 + nb * 32 + lrow;
    const float bb = bias[colc];
#pragma unroll
    for (int mbG = 0; mbG < 4; ++mbG) {
      const int rbase = bm + wr * 128 + mbG * 32 + 4 * l5;
      floatx16 v = acc[mbG][nb];
#pragma unroll
      for (int reg = 0; reg < 16; ++reg) {
        const int row = rbase + (reg & 3) + 8 * (reg >> 2);
        C[(size_t)row * N_OUT + colc] = v[reg] + bb;
      }
    }
  }
}

// ---------------- fallback (workspace too small): fp32 path ----------------
__global__ __launch_bounds__(256) void lora_xa(const float* __restrict__ x,
                                               const float* __restrict__ lA,
                                               const float* __restrict__ scale_p,
                                               float* __restrict__ t) {
  int m = blockIdx.x;
  int r = threadIdx.x & 15;
  int kcn = threadIdx.x >> 4;
  float acc = 0.f;
  const float* xr = x + (size_t)m * K_IN + kcn * 256;
  const float* ar = lA + (size_t)r * K_IN + kcn * 256;
  for (int k = 0; k < 256; k += 4) {
    float4 xv = *(const float4*)(xr + k);
    float4 av = *(const float4*)(ar + k);
    acc += xv.x * av.x + xv.y * av.y + xv.z * av.z + xv.w * av.w;
  }
  __shared__ float s[256];
  s[threadIdx.x] = acc;
  __syncthreads();
  if (threadIdx.x < 16) {
    float v = 0.f;
    for (int i = 0; i < 16; ++i) v += s[threadIdx.x + i * 16];
    t[(size_t)m * 16 + threadIdx.x] = v * (*scale_p);
  }
}

__global__ __launch_bounds__(256) void gemm_f32_fb(const float* __restrict__ X,
                                                   const float* __restrict__ W,
                                                   const float* __restrict__ bias,
                                                   const float* __restrict__ t,
                                                   const float* __restrict__ lB,
                                                   float* __restrict__ C) {
  __shared__ float sX[64][17];
  __shared__ float sW[64][17];
  int tid = threadIdx.x;
  int tx = tid & 15, ty = tid >> 4;
  int m0 = blockIdx.y * 64, n0 = blockIdx.x * 64;
  int lrow = tid >> 2, lcol = (tid & 3) * 4;
  float acc[4][4] = {};
  for (int k0 = 0; k0 < K_IN; k0 += 16) {
    __syncthreads();
    float4 xv = *(const float4*)(X + (size_t)(m0 + lrow) * K_IN + k0 + lcol);
    float4 wv = *(const float4*)(W + (size_t)(n0 + lrow) * K_IN + k0 + lcol);
    sX[lrow][lcol + 0] = xv.x; sX[lrow][lcol + 1] = xv.y;
    sX[lrow][lcol + 2] = xv.z; sX[lrow][lcol + 3] = xv.w;
    sW[lrow][lcol + 0] = wv.x; sW[lrow][lcol + 1] = wv.y;
    sW[lrow][lcol + 2] = wv.z; sW[lrow][lcol + 3] = wv.w;
    __syncthreads();
#pragma unroll
    for (int kk = 0; kk < 16; ++kk) {
      float xr[4], wr[4];
#pragma unroll
      for (int i = 0; i < 4; ++i) { xr[i] = sX[ty * 4 + i][kk]; wr[i] = sW[tx * 4 + i][kk]; }
#pragma unroll
      for (int i = 0; i < 4; ++i)
#pragma unroll
        for (int j = 0; j < 4; ++j) acc[i][j] += xr[i] * wr[j];
    }
  }
  for (int j = 0; j < 4; ++j) {
    int n = n0 + tx * 4 + j;
    float bb = bias[n];
    for (int i = 0; i < 4; ++i) {
      int m = m0 + ty * 4 + i;
      float l = 0.f;
      for (int r = 0; r < R_LORA; ++r) l += t[(size_t)m * 16 + r] * lB[(size_t)n * 16 + r];
      C[(size_t)m * N_OUT + n] = acc[i][j] + bb + l;
    }
  }
}

extern "C" void kernel_launch(void* const* d_in, const int* in_sizes, int n_in,
                              void* d_out, int out_size, void* d_ws, size_t ws_size,
                              hipStream_t stream) {
  const float* x     = (const float*)d_in[0];
  const float* W     = (const float*)d_in[1];
  const float* bias  = (const float*)d_in[2];
  const float* lB    = (const float*)d_in[3];
  const float* lA    = (const float*)d_in[4];
  const float* scale = (const float*)d_in[5];
  float* out = (float*)d_out;

  const size_t x_bytes = (size_t)M_TOK * K_IN * sizeof(bf16_t);  // 64 MB
  const size_t w_bytes = (size_t)N_OUT * K_IN * sizeof(bf16_t);  // 32 MB

  if (ws_size >= x_bytes + w_bytes) {
    bf16_t* xb = (bf16_t*)d_ws;
    bf16_t* wb = (bf16_t*)((char*)d_ws + x_bytes);
    prep_fused<<<WEFF_BLOCKS + CAST_BLOCKS, 256, 0, stream>>>(x, xb, W, lB, lA, scale, wb);
    gemm_bt256<<<(M_TOK / BM) * (N_OUT / BN), 512, 0, stream>>>(xb, wb, bias, out);
  } else {
    float* t = (float*)d_ws;
    lora_xa<<<M_TOK, 256, 0, stream>>>(x, lA, scale, t);
    gemm_f32_fb<<<dim3(N_OUT / 64, M_TOK / 64), 256, 0, stream>>>(x, W, bias, t, lB, out);
  }
}